// Round 11
// baseline (596.930 us; speedup 1.0000x reference)
//
#include <hip/hip_runtime.h>
#include <hip/hip_bf16.h>
#include <math.h>

#define NB 16384
#define NH 16
#define ND 256
#define NM 1024
#define BM 64            // rows per block
#define MB 32            // m-chunk
#define NCH (NM / MB)    // 32

typedef float f32x4 __attribute__((ext_vector_type(4)));
typedef float f32x16 __attribute__((ext_vector_type(16)));
typedef short bf16x8 __attribute__((ext_vector_type(8)));
typedef unsigned short u16;
typedef unsigned int u32;

__device__ __forceinline__ u16 f2bf(float f) {
  union { float f; unsigned u; } v; v.f = f;
  unsigned r = v.u + 0x7FFFu + ((v.u >> 16) & 1u);
  return (u16)(r >> 16);
}

// UpF[h] granules (16B = 8 bf16 along k, fixed m), chunk mc = m>>5 (16KB each):
//   flat granule g = mc*1024 + (ks*2+mt)*64 + kq*16 + m16
//   elems e: up[h][k = ks*32 + kq*8 + e][m = mc*32 + mt*16 + m16]
// Matches 16x16x32 A-frag: lane l reads granule (ks*2+mt)*64 + l  (kq=l>>4,
// m16=l&15) -> lane-linear.
__global__ __launch_bounds__(256) void prep_up(const float* __restrict__ src,
                                               u16* __restrict__ dst) {
  __shared__ float tile[64][65];
  const int h = blockIdx.z;
  const int m0 = blockIdx.x * 64, k0 = blockIdx.y * 64;
  const int tr = threadIdx.x >> 6, tc = threadIdx.x & 63;
  const float* s = src + (size_t)h * ND * NM;
#pragma unroll
  for (int i = 0; i < 16; ++i) {
    int r = i * 4 + tr;
    tile[r][tc] = s[(size_t)(k0 + r) * NM + m0 + tc];
  }
  __syncthreads();
  char* dh = (char*)dst + (size_t)h * NM * ND * 2;
#pragma unroll
  for (int g = 0; g < 2; ++g) {
    int gi = g * 256 + threadIdx.x;
    int ko = gi >> 6, m_l = gi & 63;     // k-octet 0..7, m within tile
    int k = k0 + ko * 8, m = m0 + m_l;
    int mc = m >> 5, mt = (m >> 4) & 1, m16 = m & 15;
    int ks = k >> 5, kq = (k >> 3) & 3;
    bf16x8 o;
#pragma unroll
    for (int e = 0; e < 8; ++e) o[e] = (short)f2bf(tile[ko * 8 + e][m_l]);
    *(bf16x8*)(dh + (size_t)mc * 16384 +
               (size_t)((ks * 2 + mt) * 64 + kq * 16 + m16) * 16) = o;
  }
}

// DownF[h] granules, chunk mc = m>>5 (16KB each):
//   flat granule g = mc*1024 + kh*256 + d   (kh = (m>>3)&3)
//   elems e: down[h][m = mc*32 + kh*8 + e][d]
// Matches 32x32x16 B-frag: lane reads granule (ks2*2+(l>>5))*256 + d(lane).
__global__ __launch_bounds__(256) void prep_down(const float* __restrict__ src,
                                                 u16* __restrict__ dst) {
  __shared__ float tile[64][65];
  const int h = blockIdx.z;
  const int m0 = blockIdx.x * 64, d0 = blockIdx.y * 64;
  const int tr = threadIdx.x >> 6, tc = threadIdx.x & 63;
  const float* s = src + (size_t)h * NM * ND;
#pragma unroll
  for (int i = 0; i < 16; ++i) {
    int r = i * 4 + tr;
    tile[r][tc] = s[(size_t)(m0 + r) * ND + d0 + tc];
  }
  __syncthreads();
  char* dh = (char*)dst + (size_t)h * NM * ND * 2;
#pragma unroll
  for (int g = 0; g < 2; ++g) {
    int gi = g * 256 + threadIdx.x;
    int mo = gi >> 6, d_l = gi & 63;     // m-octet 0..7, d within tile
    int m = m0 + mo * 8, d = d0 + d_l;
    int mc = m >> 5, kh = (m >> 3) & 3;
    bf16x8 o;
#pragma unroll
    for (int e = 0; e < 8; ++e) o[e] = (short)f2bf(tile[mo * 8 + e][d_l]);
    *(bf16x8*)(dh + (size_t)mc * 16384 + (size_t)(kh * 256 + d) * 16) = o;
  }
}

// xp[b][i] = bf16(x[b][perm[i]])
__global__ __launch_bounds__(1024) void permute_x(const float* __restrict__ x,
                                                  const int* __restrict__ perm,
                                                  u16* __restrict__ xp) {
  const int b = blockIdx.x;
  const int t = threadIdx.x;
  const float* xr = x + (size_t)b * 4096;
  int4 p = *(const int4*)(perm + t * 4);
  ushort4 o;
  o.x = f2bf(xr[p.x]); o.y = f2bf(xr[p.y]);
  o.z = f2bf(xr[p.z]); o.w = f2bf(xr[p.w]);
  *(ushort4*)(xp + (size_t)b * 4096 + t * 4) = o;
}

// out[b][j] = out[b][unperm[j]] (in place, one row per block)
__global__ __launch_bounds__(1024) void unpermute_out(float* __restrict__ out,
                                                      const int* __restrict__ unperm) {
  __shared__ float row[4096];
  const int b = blockIdx.x;
  const int t = threadIdx.x;
  float* orow = out + (size_t)b * 4096;
  *(f32x4*)(row + t * 4) = *(const f32x4*)(orow + t * 4);
  __syncthreads();
  int4 u = *(const int4*)(unperm + t * 4);
  f32x4 v;
  v.x = row[u.x]; v.y = row[u.y]; v.z = row[u.z]; v.w = row[u.w];
  *(f32x4*)(orow + t * 4) = v;
}

// 8-wave (512-thread) producer/consumer MLP, 72KB LDS -> 2 BLOCKS/CU.
// R10 (1024thr, 160KB, 1 block/CU) showed sum-of-pipes == region time: the
// block-wide barrier convoys all waves, GELU runs with MFMA/LDS idle, and
// nothing fills the gaps. Two independent blocks (4 waves/SIMD, cap 128)
// let block Y's MFMA/LDS work cover block X's barrier+GELU tail (m114).
//   A-waves (w<4, rtA=w): 16-row strip, 16x16x32 swapped MFMA (xr 32 VGPR):
//     per chunk 16 reads + 16 MFMAs (2 indep pa chains) + GELU -> Ps[c]
//     (cvt_pk b64, lane-linear).
//   B-waves (w>=4, dq=w-4): 64r x 64d quarter, 32x32x16: per chunk
//     2 ks x (a0,a1 + 2 Ds reads, each reused x2) = 8 reads / 8 MFMAs.
// All LDS accesses lane-linear in fragment-granule order (conflict-free);
// staging is pure linear gload_lds from the pre-transformed weights.
// Region i: A{stage Us(i+1)->c^1; A(i) from Us[c]; GELU->Ps[c]} ||
//           B{stage Ds(i)->c; if i>0 B(i-1) from Ps[c^1],Ds[c^1]}
//           -> per-branch waitcnt + ONE barrier (equal counts both roles).
__global__ __launch_bounds__(512, 4) void mlp_fused(
    const u16* __restrict__ xp,
    const u16* __restrict__ upF,
    const u16* __restrict__ downF,
    float* __restrict__ out) {
  __shared__ __align__(16) u16 Us[2][MB * ND];   // 2x16KB [ks8*mt2][kq4][m16][8]
  __shared__ __align__(16) u16 Ds[2][ND * MB];   // 2x16KB [kh4][d256][8]
  __shared__ __align__(16) u16 Ps[2][BM * MB];   // 2x4KB  [kh4][r64][8]

  const int h   = blockIdx.y;
  const int rb  = blockIdx.x;
  const int tid = threadIdx.x;
  const int w   = tid >> 6;
  const int l   = tid & 63;
  const int row0 = rb * BM;

  const char* upH = (const char*)upF + (size_t)h * NM * ND * 2;
  const char* dnH = (const char*)downF + (size_t)h * NM * ND * 2;

  // ---- prologue: all 8 waves stage Us(0) (2 granules/thread), then barrier
#pragma unroll
  for (int j = 0; j < 2; ++j) {
    int t = j * 512 + tid;
    __builtin_amdgcn_global_load_lds(
        (const __attribute__((address_space(1))) void*)(upH + (size_t)t * 16),
        (__attribute__((address_space(3))) void*)((char*)&Us[0][0] + (size_t)t * 16),
        16, 0, 0);
  }
  asm volatile("s_waitcnt vmcnt(0)" ::: "memory");
  __builtin_amdgcn_s_barrier();

  if (w < 4) {
    // ================= producer (A): 16x16x32 swapped =================
    const int rtA = w;            // 16-row strip
    const int ll  = l & 15;       // x-row within strip (frag col)
    const int q   = l >> 4;       // k-quarter (frag k = q*8+e)

    // X fragments: row = row0 + rtA*16 + ll, k = ks*32 + q*8 + e. 32 VGPR.
    bf16x8 xr[8];
    {
      const u16* px = xp + (size_t)(row0 + rtA * 16 + ll) * 4096 + h * ND;
#pragma unroll
      for (int ks = 0; ks < 8; ++ks)
        xr[ks] = *(const bf16x8*)(px + ks * 32 + q * 8);
    }
    // Ps write slot: granule (kh = mt*2 + (q>>1), r = rtA*16+ll), byte (q&1)*8
    char* const psW = (char*)&Ps[0][0] + (size_t)(rtA * 16 + ll) * 16 + (q & 1) * 8;
    const int khW = (q >> 1);     // + mt*2 per mt

    for (int i = 0; i < NCH; ++i) {
      const int c = i & 1;
      // stage Us(i+1) -> buf c^1 (A-threads: tid<256, 4 granules each)
      if (i + 1 < NCH) {
        const char* src = upH + (size_t)(i + 1) * 16384;
#pragma unroll
        for (int j = 0; j < 4; ++j) {
          int t = j * 256 + tid;
          __builtin_amdgcn_global_load_lds(
              (const __attribute__((address_space(1))) void*)(src + (size_t)t * 16),
              (__attribute__((address_space(3))) void*)((char*)&Us[c ^ 1][0] + (size_t)t * 16),
              16, 0, 0);
        }
      }

      // A(i): P[16r x 32m] via 2 independent 8-chains (one per mt)
      f32x4 pa[2];
#pragma unroll
      for (int mt = 0; mt < 2; ++mt) { f32x4 z = {0.f, 0.f, 0.f, 0.f}; pa[mt] = z; }
      {
        const char* ub = (const char*)&Us[c][0] + (size_t)l * 16;
        __builtin_amdgcn_s_setprio(1);
#pragma unroll
        for (int ks = 0; ks < 8; ++ks)
#pragma unroll
          for (int mt = 0; mt < 2; ++mt) {
            bf16x8 av = *(const bf16x8*)(ub + (size_t)(ks * 2 + mt) * 1024);
            pa[mt] = __builtin_amdgcn_mfma_f32_16x16x32_bf16(av, xr[ks], pa[mt], 0, 0, 0);
          }
        __builtin_amdgcn_s_setprio(0);
      }

      // gelu -> cvt_pk pack -> 1x ds_write_b64 per mt (lane-linear)
      // pa[mt][r4] = P[r = rtA*16+ll][m = mt*16 + q*4 + r4]
#pragma unroll
      for (int mt = 0; mt < 2; ++mt) {
        float gv[4];
#pragma unroll
        for (int r4 = 0; r4 < 4; ++r4) {
          float v = pa[mt][r4];
          float p = __builtin_fmaf(0.1029433f, v * v, 2.3022082f);
          float ex = __builtin_amdgcn_exp2f(v * p);
          float r = __builtin_amdgcn_rcpf(ex + 1.0f);
          gv[r4] = __builtin_fmaf(-v, r, v);
        }
        u32 w0, w1;
        asm("v_cvt_pk_bf16_f32 %0, %1, %2" : "=v"(w0) : "v"(gv[0]), "v"(gv[1]));
        asm("v_cvt_pk_bf16_f32 %0, %1, %2" : "=v"(w1) : "v"(gv[2]), "v"(gv[3]));
        uint2 pk; pk.x = w0; pk.y = w1;
        *(uint2*)(psW + (size_t)c * (BM * MB * 2) +
                  (size_t)(mt * 2 + khW) * 1024) = pk;
      }

      __builtin_amdgcn_sched_barrier(0);
      asm volatile("s_waitcnt lgkmcnt(0)" ::: "memory");   // Ps published
      asm volatile("s_waitcnt vmcnt(0)" ::: "memory");     // Us(i+1) landed
      __builtin_amdgcn_s_barrier();
      __builtin_amdgcn_sched_barrier(0);
    }
  } else {
    // ================= consumer (B): 32x32x16 =================
    const int dq = w - 4;         // 64-d quarter
    const int lo = l & 31;
    const int hi = l >> 5;
    const int tb = tid - 256;

    f32x16 ca[2][2];   // [rt2][dt] 32x32 tiles: 64r x 64d -> 64 VGPR
#pragma unroll
    for (int rt2 = 0; rt2 < 2; ++rt2)
#pragma unroll
      for (int dt = 0; dt < 2; ++dt)
#pragma unroll
        for (int e = 0; e < 16; ++e)
          ca[rt2][dt][e] = 0.f;

    for (int i = 0; i < NCH; ++i) {
      const int c = i & 1;
      // stage Ds(i) -> buf c (B-threads, 4 granules each)
      {
        const char* src = dnH + (size_t)i * 16384;
#pragma unroll
        for (int j = 0; j < 4; ++j) {
          int t = j * 256 + tb;
          __builtin_amdgcn_global_load_lds(
              (const __attribute__((address_space(1))) void*)(src + (size_t)t * 16),
              (__attribute__((address_space(3))) void*)((char*)&Ds[c][0] + (size_t)t * 16),
              16, 0, 0);
        }
      }

      // B(i-1): C += Ps[c^1] @ Ds[c^1]
      if (i > 0) {
        const char* psb = (const char*)&Ps[c ^ 1][0] + (size_t)(hi * 64 + lo) * 16;
        const char* dsb = (const char*)&Ds[c ^ 1][0] +
                          (size_t)hi * 4096 + (size_t)(dq * 64 + lo) * 16;
        __builtin_amdgcn_s_setprio(1);
#pragma unroll
        for (int ks = 0; ks < 2; ++ks) {
          bf16x8 a0 = *(const bf16x8*)(psb + ks * 2048);
          bf16x8 a1 = *(const bf16x8*)(psb + ks * 2048 + 512);
#pragma unroll
          for (int dt = 0; dt < 2; ++dt) {
            bf16x8 bv = *(const bf16x8*)(dsb + ks * 8192 + dt * 512);
            ca[0][dt] = __builtin_amdgcn_mfma_f32_32x32x16_bf16(a0, bv, ca[0][dt], 0, 0, 0);
            ca[1][dt] = __builtin_amdgcn_mfma_f32_32x32x16_bf16(a1, bv, ca[1][dt], 0, 0, 0);
          }
        }
        __builtin_amdgcn_s_setprio(0);
      }

      __builtin_amdgcn_sched_barrier(0);
      asm volatile("s_waitcnt vmcnt(0)" ::: "memory");     // Ds(i) landed
      __builtin_amdgcn_s_barrier();
      __builtin_amdgcn_sched_barrier(0);
    }

    // final B(NCH-1): Ps[1], Ds[1]
    {
      const int c = (NCH - 1) & 1;
      const char* psb = (const char*)&Ps[c][0] + (size_t)(hi * 64 + lo) * 16;
      const char* dsb = (const char*)&Ds[c][0] +
                        (size_t)hi * 4096 + (size_t)(dq * 64 + lo) * 16;
      __builtin_amdgcn_s_setprio(1);
#pragma unroll
      for (int ks = 0; ks < 2; ++ks) {
        bf16x8 a0 = *(const bf16x8*)(psb + ks * 2048);
        bf16x8 a1 = *(const bf16x8*)(psb + ks * 2048 + 512);
#pragma unroll
        for (int dt = 0; dt < 2; ++dt) {
          bf16x8 bv = *(const bf16x8*)(dsb + ks * 8192 + dt * 512);
          ca[0][dt] = __builtin_amdgcn_mfma_f32_32x32x16_bf16(a0, bv, ca[0][dt], 0, 0, 0);
          ca[1][dt] = __builtin_amdgcn_mfma_f32_32x32x16_bf16(a1, bv, ca[1][dt], 0, 0, 0);
        }
      }
      __builtin_amdgcn_s_setprio(0);
    }

    // epilogue: out[b][h*256+d], 32 consecutive d per lane-group (coalesced)
    // C-layout 32x32: col d = lo, row = (reg&3) + 8*(reg>>2) + 4*hi.
#pragma unroll
    for (int rt2 = 0; rt2 < 2; ++rt2)
#pragma unroll
      for (int dt = 0; dt < 2; ++dt) {
        const int d = h * ND + dq * 64 + dt * 32 + lo;
#pragma unroll
        for (int reg = 0; reg < 16; ++reg) {
          int r = rt2 * 32 + (reg & 3) + 8 * (reg >> 2) + 4 * hi;
          out[(size_t)(row0 + r) * 4096 + d] = ca[rt2][dt][reg];
        }
      }
  }
}

extern "C" void kernel_launch(void* const* d_in, const int* in_sizes, int n_in,
                              void* d_out, int out_size, void* d_ws, size_t ws_size,
                              hipStream_t stream) {
  const float* x    = (const float*)d_in[0];
  const float* up   = (const float*)d_in[1];
  const float* down = (const float*)d_in[2];
  const int* perm   = (const int*)d_in[3];
  const int* unperm = (const int*)d_in[4];
  float* out = (float*)d_out;

  u16* upF   = (u16*)d_ws;                                   // 8 MB
  u16* downF = upF + (size_t)NH * NM * ND;                   // 8 MB
  u16* xp    = downF + (size_t)NH * NM * ND;                 // 128 MB

  // weights -> fragment-granule order (one-time, coalesced tile transposes)
  prep_up<<<dim3(NM / 64, ND / 64, NH), 256, 0, stream>>>(up, upF);
  prep_down<<<dim3(NM / 64, ND / 64, NH), 256, 0, stream>>>(down, downF);
  // xp[b][i] = bf16(x[b][perm[i]])
  permute_x<<<NB, 1024, 0, stream>>>(x, perm, xp);
  // main fused MLP: 512 thr (4A+4B), 72KB LDS, 2 blocks/CU.
  mlp_fused<<<dim3(NB / BM, NH), 512, 0, stream>>>(xp, upF, downF, out);
  // in-place feature unpermute
  unpermute_out<<<NB, 1024, 0, stream>>>(out, unperm);
}